// Round 7
// baseline (483.852 us; speedup 1.0000x reference)
//
#include <hip/hip_runtime.h>

#define DD    256    // feature dim
#define CC    100    // num classes
#define TPB   1024   // accum threads per block (16 waves)
#define NBACC 256    // accum blocks (one per CU on full chip)
#define ABT   256    // argmax threads per block

// Workspace layout (bytes):
//   [0, 102400)        : g_sums   (CC*DD f32, TRANSPOSED position layout)
//   [102400, 102800)   : g_counts (CC int)
//   [102800, 102808)   : g_sumsq  (1 double)
//   [103424, +4N)      : cls      (N int)
//   [aligned, ...)     : partials (NBACC * CC*DD f32)
#define WS_SUMS_OFF   0
#define WS_COUNTS_OFF (CC * DD * 4)
#define WS_SUMSQ_OFF  (WS_COUNTS_OFF + CC * 4)
#define WS_HDR        (WS_SUMSQ_OFF + 8)
#define WS_CLS_OFF    103424

// ---------------- kernel A: per-row argmax (8-deep MLP batches) --------------
__global__ __launch_bounds__(ABT) void k_argmax(
        const float* __restrict__ labels,
        int*   __restrict__ cls,
        int*   __restrict__ g_counts,
        int N)
{
    __shared__ int s_cnt[CC];
    const int tid = threadIdx.x;
    if (tid < CC) s_cnt[tid] = 0;
    __syncthreads();

    const long long row = (long long)blockIdx.x * ABT + tid;
    if (row < (long long)N) {
        const float4* l4 = (const float4*)(labels + row * (long long)CC);
        float best = -3.4e38f;
        int   bi   = 0;
        float4 q[8];
        #pragma unroll
        for (int b = 0; b < 3; ++b) {               // 3 batches of 8 loads
            #pragma unroll
            for (int j = 0; j < 8; ++j) q[j] = l4[b * 8 + j];
            #pragma unroll
            for (int j = 0; j < 8; ++j) {           // strict > = first-max
                const int e = (b * 8 + j) * 4;
                if (q[j].x > best) { best = q[j].x; bi = e; }
                if (q[j].y > best) { best = q[j].y; bi = e + 1; }
                if (q[j].z > best) { best = q[j].z; bi = e + 2; }
                if (q[j].w > best) { best = q[j].w; bi = e + 3; }
            }
        }
        {                                            // tail: elements 96..99
            const float4 qz = l4[24];
            if (qz.x > best) { best = qz.x; bi = 96; }
            if (qz.y > best) { best = qz.y; bi = 97; }
            if (qz.z > best) { best = qz.z; bi = 98; }
            if (qz.w > best) { best = qz.w; bi = 99; }
        }
        cls[row] = bi;
        atomicAdd(&s_cnt[bi], 1);                    // native int LDS atomic
    }
    __syncthreads();
    if (tid < CC) {
        const int c = s_cnt[tid];
        if (c) atomicAdd(&g_counts[tid], c);
    }
}

// ---------------- kernel B: full-row float4 class-sum accumulate -------------
// One wave instruction loads ONE full feature row (64 lanes x float4 = 1 KB).
// LDS tile stored TRANSPOSED: element (4*lane+k) of class c lives at
// s_sums[c*DD + k*64 + lane]  -> ds_add bank = lane%32 (free 2-way).
__global__ __launch_bounds__(TPB) void k_accum(
        const float* __restrict__ feats,
        const int*   __restrict__ cls,
        float* __restrict__ g_partials,
        float* __restrict__ g_sums,
        double* __restrict__ g_sumsq,
        int use_partials, int N)
{
    __shared__ float  s_sums[CC * DD];   // 100 KB -> 1 block/CU, 16 waves
    __shared__ double s_red[TPB / 64];

    const int tid  = threadIdx.x;
    const int lane = tid & 63;
    const int wid  = tid >> 6;

    for (int i = tid; i < CC * DD; i += TPB) s_sums[i] = 0.f;
    __syncthreads();

    float sumsq = 0.f;

    const int ngrp = (N + TPB - 1) / TPB;            // 1024-row groups
    for (int g = blockIdx.x; g < ngrp; g += NBACC) {
        const int rbase = g * TPB + wid * 64;        // this wave's 64 rows

        // classes of these 64 rows, one per lane (coalesced dword load)
        const int myrow = rbase + lane;
        const int c64 = (myrow < N) ? cls[myrow] : -1;

        #pragma unroll
        for (int h = 0; h < 4; ++h) {                // 4 batches x 16 rows
            const int r0 = rbase + h * 16;

            // ---- 16 independent full-row loads (16 KB in flight) ----
            float4 f[16];
            #pragma unroll
            for (int i = 0; i < 16; ++i) {
                const int r  = r0 + i;
                const int rr = (r < N) ? r : 0;      // branchless clamp
                f[i] = ((const float4*)(feats + (size_t)rr * DD))[lane];
            }

            #pragma unroll
            for (int i = 0; i < 16; ++i) {
                const int c = __shfl(c64, h * 16 + i);  // wave-uniform (readlane)
                if (c < 0) continue;                    // OOB row: uniform skip
                sumsq += f[i].x * f[i].x + f[i].y * f[i].y
                       + f[i].z * f[i].z + f[i].w * f[i].w;
                float* dst = &s_sums[c * DD + lane];    // uniform base
                unsafeAtomicAdd(dst +   0, f[i].x);     // pos k*64+lane, k=0..3
                unsafeAtomicAdd(dst +  64, f[i].y);
                unsafeAtomicAdd(dst + 128, f[i].z);
                unsafeAtomicAdd(dst + 192, f[i].w);
            }
        }
    }

    // ---- sumsq: wave reduce -> block reduce -> one f64 atomic per block ----
    double ds = (double)sumsq;
    #pragma unroll
    for (int off = 1; off < 64; off <<= 1) ds += __shfl_xor(ds, off);
    if (lane == 0) s_red[wid] = ds;
    __syncthreads();   // also drains all ds_add_f32
    if (tid == 0) {
        double t = 0.0;
        #pragma unroll
        for (int i = 0; i < TPB / 64; ++i) t += s_red[i];
        atomicAdd(g_sumsq, t);
    }

    // ---- flush (positional copy; layout stays transposed) ----
    if (use_partials) {
        float* dst = g_partials + (size_t)blockIdx.x * (CC * DD);
        for (int i = tid; i < CC * DD; i += TPB) dst[i] = s_sums[i];
    } else {
        for (int i = tid; i < CC * DD; i += TPB) {
            const float s = s_sums[i];
            if (s != 0.f) unsafeAtomicAdd(&g_sums[i], s);
        }
    }
}

// ---------------- reduce partials -> g_sums (positional) ---------------------
__global__ __launch_bounds__(DD) void k_reduce(
        const float* __restrict__ g_partials,
        float* __restrict__ g_sums,
        int nblocks)
{
    const int c = blockIdx.x;            // class
    const int p = threadIdx.x;           // position within class row
    const float* src = g_partials + c * DD + p;
    double acc = 0.0;
    for (int b = 0; b < nblocks; ++b)
        acc += (double)src[(size_t)b * (CC * DD)];   // coalesced across threads
    g_sums[c * DD + p] = (float)acc;
}

// ---------------- finalize ----------------------------------------------------
// Layout-transparent: each thread owns one POSITION (= one dim, permuted);
// all loss terms are sums over (class, dim), and colmean is per-dim — both
// invariant under a per-dim permutation.
__global__ __launch_bounds__(DD) void affinity_finalize(
        const float* __restrict__ g_sums,
        const int*   __restrict__ g_counts,
        const double* __restrict__ g_sumsq,
        float* __restrict__ out)
{
    const int d = threadIdx.x;

    double colsum = 0.0, s2 = 0.0, dot = 0.0, cc = 0.0;
    for (int c = 0; c < CC; ++c) {
        const int    cnt = g_counts[c];
        const float  s   = g_sums[c * DD + d];
        const double center = (cnt > 0 ? (double)s / (double)cnt : 0.0) + 1e-6;
        colsum += center;
        s2     += center * center;
        dot    += center * (double)s;
        cc     += (double)cnt * center * center;
    }
    double interp = s2 - colsum * colsum / (double)CC;

    __shared__ double red0[DD], red1[DD], red2[DD];
    red0[d] = dot; red1[d] = cc; red2[d] = interp;
    __syncthreads();
    for (int off = DD / 2; off > 0; off >>= 1) {
        if (d < off) {
            red0[d] += red0[d + off];
            red1[d] += red1[d + off];
            red2[d] += red2[d + off];
        }
        __syncthreads();
    }
    if (d == 0) {
        const double intra = *g_sumsq - 2.0 * red0[0] + red1[0];
        const double inter = red2[0] / (double)CC;
        out[0] = (float)(intra / (inter + 1e-6));
    }
}

extern "C" void kernel_launch(void* const* d_in, const int* in_sizes, int n_in,
                              void* d_out, int out_size, void* d_ws, size_t ws_size,
                              hipStream_t stream)
{
    const float* feats  = (const float*)d_in[0];
    const float* labels = (const float*)d_in[1];
    const int N = in_sizes[0] / DD;

    float*  g_sums   = (float*)((char*)d_ws + WS_SUMS_OFF);
    int*    g_counts = (int*)((char*)d_ws + WS_COUNTS_OFF);
    double* g_sumsq  = (double*)((char*)d_ws + WS_SUMSQ_OFF);
    int*    cls      = (int*)((char*)d_ws + WS_CLS_OFF);

    const size_t part_off = ((size_t)WS_CLS_OFF + (size_t)N * 4 + 255) & ~(size_t)255;
    float* g_partials = (float*)((char*)d_ws + part_off);

    const size_t need = part_off + (size_t)NBACC * (CC * DD) * 4;
    const int use_partials = (ws_size >= need) ? 1 : 0;

    hipMemsetAsync(d_ws, 0, WS_HDR, stream);     // zero sums/counts/sumsq

    const int nblocksA = (N + ABT - 1) / ABT;
    k_argmax<<<nblocksA, ABT, 0, stream>>>(labels, cls, g_counts, N);

    k_accum<<<NBACC, TPB, 0, stream>>>(feats, cls, g_partials, g_sums,
                                       g_sumsq, use_partials, N);
    if (use_partials)
        k_reduce<<<CC, DD, 0, stream>>>(g_partials, g_sums, NBACC);

    affinity_finalize<<<1, DD, 0, stream>>>(g_sums, g_counts, g_sumsq,
                                            (float*)d_out);
}